// Round 3
// baseline (605.406 us; speedup 1.0000x reference)
//
#include <hip/hip_runtime.h>
#include <math.h>

// CRF layer: B=2048 sequences, T=512 max steps, C=32 tags.
// out = [ tags as float (B*T) | loss (1) ], total 1048577 floats.
#define BB 2048
#define TT 512
#define CC 32

#if __has_builtin(__builtin_amdgcn_exp2f)
#define EXP2F __builtin_amdgcn_exp2f
#else
#define EXP2F exp2f
#endif
#if __has_builtin(__builtin_amdgcn_logf)
#define LOG2F __builtin_amdgcn_logf   // v_log_f32 computes log2
#else
#define LOG2F log2f
#endif

#define LOG2E 1.4426950408889634f
#define LN2   0.6931471805599453f

__global__ void zero_loss_kernel(float* __restrict__ out) {
  if (threadIdx.x == 0) out[(size_t)BB * TT] = 0.0f;
}

// One wave (64 lanes) per batch element, one wave per block (no barriers:
// DS pipe is in-order within a wave, so LDS write -> read is safe).
// lane = h*32 + c : c = current tag, h selects which 16 prev-tags this lane
// reduces over. Viterbi runs in natural domain (bitwise-exact vs reference);
// forward log-alpha runs in log2 domain (native v_exp/v_log, no arg muls).
__global__ __launch_bounds__(64, 2) void crf_kernel(
    const float* __restrict__ logits,     // [B, T, C]
    const int*   __restrict__ seqlen,     // [B]
    const int*   __restrict__ labels,     // [B, T]
    const float* __restrict__ trans,      // [C, C]  trans[p*C + c]
    float*       __restrict__ out)        // [B*T + 1]
{
  __shared__ unsigned char bp_s[(TT - 1) * CC];       // 16,352 B backpointers
  __shared__ __align__(16) float avs[CC];             // viterbi alpha (natural)
  __shared__ __align__(16) float afs[CC];             // forward alpha (log2 dom)

  const int lane = threadIdx.x;          // 0..63
  const int c    = lane & 31;
  const int h    = lane >> 5;
  const int b    = blockIdx.x;

  const int len = seqlen[b];
  const float* lg  = logits + (size_t)b * TT * CC;
  const int*   lab = labels + (size_t)b * TT;
  const size_t bT  = (size_t)b * TT;

  // my 16 transition entries: tr[i] = trans[(h*16+i)][c]; tr2 = tr * log2e
  float tr[16], tr2[16];
#pragma unroll
  for (int i = 0; i < 16; ++i) {
    tr[i]  = trans[(h * 16 + i) * CC + c];
    tr2[i] = tr[i] * LOG2E;
  }

  // ---------- init t = 0 ----------
  float av = lg[c];
  float A  = av * LOG2E;
  if (h == 0) { avs[c] = av; afs[c] = A; }

  // prologue exchange (in-order DS within the wave makes this safe)
  float pav[16], paf[16];
  {
    const float4* avp = (const float4*)(avs + h * 16);
    const float4* afp = (const float4*)(afs + h * 16);
#pragma unroll
    for (int q = 0; q < 4; ++q) ((float4*)pav)[q] = avp[q];
#pragma unroll
    for (int q = 0; q < 4; ++q) ((float4*)paf)[q] = afp[q];
  }

  // logits register pipeline, 3 steps deep, clamped to last valid row
  const int lastrow = (len - 1) * CC;
  int r1 = 1 * CC > lastrow ? lastrow : 1 * CC;
  int r2 = 2 * CC > lastrow ? lastrow : 2 * CC;
  int r3 = 3 * CC > lastrow ? lastrow : 3 * CC;
  float l0 = lg[r1 + c];
  float l1 = lg[r2 + c];
  float l2 = lg[r3 + c];

  // ---------- fused Viterbi + forward recursion ----------
  for (int t = 1; t < len; ++t) {
    float logit_c = l0;
    l0 = l1; l1 = l2;
    int rn = (t + 3) * CC;
    l2 = lg[(rn > lastrow ? lastrow : rn) + c];

    // ---- Viterbi half (natural domain, exact) ----
    float S[16];
#pragma unroll
    for (int i = 0; i < 16; ++i) S[i] = pav[i] + tr[i];

    // first-index-exact argmax: descending >= scan within groups of 4,
    // then descending >= combine of groups (== full descending linear scan)
    float gv[4]; int gi[4];
#pragma unroll
    for (int g = 0; g < 4; ++g) {
      float bv = S[4 * g + 3]; int bidx = 4 * g + 3;
      if (S[4 * g + 2] >= bv) { bv = S[4 * g + 2]; bidx = 4 * g + 2; }
      if (S[4 * g + 1] >= bv) { bv = S[4 * g + 1]; bidx = 4 * g + 1; }
      if (S[4 * g + 0] >= bv) { bv = S[4 * g + 0]; bidx = 4 * g + 0; }
      gv[g] = bv; gi[g] = bidx;
    }
    float best = gv[3]; int bi = gi[3];
    if (gv[2] >= best) { best = gv[2]; bi = gi[2]; }
    if (gv[1] >= best) { best = gv[1]; bi = gi[1]; }
    if (gv[0] >= best) { best = gv[0]; bi = gi[0]; }
    int bpi = h * 16 + bi;

    // cross-half exchange (issue early; hide latency under F adds)
    float ov = __shfl_xor(best, 32);
    int   oi = __shfl_xor(bpi, 32);

    // ---- forward adds (independent of viterbi; hides shfl latency) ----
    float F[16];
#pragma unroll
    for (int i = 0; i < 16; ++i) F[i] = paf[i] + tr2[i];

    bool take = (ov > best) || (ov == best && oi < bpi);  // lower p wins ties
    best = take ? ov : best;
    bpi  = take ? oi : bpi;
    av = logit_c + best;

    if (h == 0) {
      avs[c] = av;
      bp_s[(t - 1) * CC + c] = (unsigned char)bpi;
    }
    // early read of next-step viterbi alphas (latency hidden by forward tail)
    {
      const float4* avp = (const float4*)(avs + h * 16);
#pragma unroll
      for (int q = 0; q < 4; ++q) ((float4*)pav)[q] = avp[q];
    }

    // ---- forward tail (log2 domain) ----
    float m8[8];
#pragma unroll
    for (int k = 0; k < 8; ++k) m8[k] = fmaxf(F[k], F[k + 8]);
#pragma unroll
    for (int w = 4; w >= 1; w >>= 1)
#pragma unroll
      for (int k = 0; k < 4; ++k)
        if (k < w) m8[k] = fmaxf(m8[k], m8[k + w]);
    float fmx = m8[0];
    float om = __shfl_xor(fmx, 32);
    float m  = fmaxf(fmx, om);

    float e[16];
#pragma unroll
    for (int i = 0; i < 16; ++i) e[i] = EXP2F(F[i] - m);
    float s8[8];
#pragma unroll
    for (int k = 0; k < 8; ++k) s8[k] = e[k] + e[k + 8];
    float s4a = s8[0] + s8[4], s4b = s8[1] + s8[5];
    float s4c = s8[2] + s8[6], s4d = s8[3] + s8[7];
    float s = (s4a + s4b) + (s4c + s4d);
    s += __shfl_xor(s, 32);

    A = logit_c * LOG2E + (m + LOG2F(s));

    if (h == 0) afs[c] = A;
    // read next-step forward alphas (latency hidden by next viterbi block)
    {
      const float4* afp = (const float4*)(afs + h * 16);
#pragma unroll
      for (int q = 0; q < 4; ++q) ((float4*)paf)[q] = afp[q];
    }
  }

  // ---------- gold-path score (unary + binary), lane-parallel over t ----------
  float uacc = 0.0f, bacc = 0.0f;
#pragma unroll
  for (int j = 0; j < 8; ++j) {
    int t = lane + 64 * j;
    if (t < len) {
      int lt = lab[t];
      uacc += lg[t * CC + lt];
      if (t + 1 < len) {
        int ln = lab[t + 1];
        bacc += trans[lt * CC + ln];
      }
    }
  }
#pragma unroll
  for (int d = 32; d >= 1; d >>= 1) {
    uacc += __shfl_xor(uacc, d);
    bacc += __shfl_xor(bacc, d);
  }

  // ---------- last tag: argmax over c (first index on ties) ----------
  float v = av; int idx = c;
#pragma unroll
  for (int d = 1; d < 32; d <<= 1) {
    float v2 = __shfl_xor(v, d, 32);
    int   i2 = __shfl_xor(idx, d, 32);
    if (v2 > v || (v2 == v && i2 < idx)) { v = v2; idx = i2; }
  }

  // ---------- log partition (log2 domain -> natural) ----------
  float mm = A;
#pragma unroll
  for (int d = 1; d < 32; d <<= 1) mm = fmaxf(mm, __shfl_xor(mm, d, 32));
  float ss = EXP2F(A - mm);
#pragma unroll
  for (int d = 1; d < 32; d <<= 1) ss += __shfl_xor(ss, d, 32);
  float log_norm = LN2 * (mm + LOG2F(ss));

  // ---------- backtrace + outputs ----------
  if (lane == 0) {
    int tag = idx;
    for (int t = len - 1; t > 0; --t) {
      out[bT + t] = (float)tag;
      tag = bp_s[(t - 1) * CC + tag];
    }
    out[bT] = (float)tag;

    float ll = uacc + bacc - log_norm;
    atomicAdd(out + (size_t)BB * TT, -ll * (1.0f / BB));
  }
  // zero-fill padded positions t >= len
  for (int t = len + lane; t < TT; t += 64) out[bT + t] = 0.0f;
}

extern "C" void kernel_launch(void* const* d_in, const int* in_sizes, int n_in,
                              void* d_out, int out_size, void* d_ws, size_t ws_size,
                              hipStream_t stream) {
  const float* logits = (const float*)d_in[0];
  const int*   seqlen = (const int*)d_in[1];
  const int*   labels = (const int*)d_in[2];
  const float* trans  = (const float*)d_in[3];
  float* out = (float*)d_out;

  zero_loss_kernel<<<1, 64, 0, stream>>>(out);
  crf_kernel<<<dim3(BB), dim3(64), 0, stream>>>(logits, seqlen, labels, trans, out);
}

// Round 4
// 589.169 us; speedup vs baseline: 1.0276x; 1.0276x over previous
//
#include <hip/hip_runtime.h>
#include <math.h>

// CRF layer: B=2048 sequences, T=512 max steps, C=32 tags.
// out = [ tags as float (B*T) | loss (1) ], total 1048577 floats.
#define BB 2048
#define TT 512
#define CC 32

#if __has_builtin(__builtin_amdgcn_exp2f)
#define EXP2F __builtin_amdgcn_exp2f
#else
#define EXP2F exp2f
#endif
#if __has_builtin(__builtin_amdgcn_logf)
#define LOG2F __builtin_amdgcn_logf   // v_log_f32 computes log2
#else
#define LOG2F log2f
#endif

#define LOG2E 1.4426950408889634f
#define LN2   0.6931471805599453f

__global__ void zero_loss_kernel(float* __restrict__ out) {
  if (threadIdx.x == 0) out[(size_t)BB * TT] = 0.0f;
}

// One wave (64 lanes) per batch element, one wave per block (no barriers:
// DS pipe is in-order within a wave). lane = h*32 + c.
// Per step the LDS/DS dependency depth is 3: read pairs -> one shuffle
// round (4 independent xor-32 shuffles) -> one b64 write.
// Forward logsumexp exps against the LOCAL half max, then rescales after the
// exchange: s = sl*2^(fmx-m) + os*2^(ofm-m). Only h==0 publishes state.
__global__ __launch_bounds__(64, 2) void crf_kernel(
    const float* __restrict__ logits,     // [B, T, C]
    const int*   __restrict__ seqlen,     // [B]
    const int*   __restrict__ labels,     // [B, T]
    const float* __restrict__ trans,      // [C, C]  trans[p*C + c]
    float*       __restrict__ out)        // [B*T + 1]
{
  __shared__ __align__(16) unsigned char bp_s[(TT - 1) * CC]; // 16,352 B
  __shared__ __align__(16) float axs[2 * CC];   // interleaved (av, A) pairs
  __shared__ unsigned char tag_s[TT];

  const int lane = threadIdx.x;          // 0..63
  const int c    = lane & 31;
  const int h    = lane >> 5;
  const int b    = blockIdx.x;

  const int len = seqlen[b];
  const float* lg  = logits + (size_t)b * TT * CC;
  const int*   lab = labels + (size_t)b * TT;
  const size_t bT  = (size_t)b * TT;

  // my 16 transition entries: tr[i] = trans[(h*16+i)][c]; tr2 = tr * log2e
  float tr[16], tr2[16];
#pragma unroll
  for (int i = 0; i < 16; ++i) {
    tr[i]  = trans[(h * 16 + i) * CC + c];
    tr2[i] = tr[i] * LOG2E;
  }

  // ---------- init t = 0 ----------
  float av = lg[c];          // viterbi score (natural domain, exact)
  float A  = av * LOG2E;     // forward log2-alpha
  if (h == 0) ((float2*)axs)[c] = make_float2(av, A);

  // my half's 16 (av,A) pairs = 8 float4s
  const float4* axp = ((const float4*)axs) + h * 8;
  float4 q[8];
#pragma unroll
  for (int j = 0; j < 8; ++j) q[j] = axp[j];

  // logits register pipeline, 3 steps deep, clamped to last valid row
  const int lastrow = (len - 1) * CC;
  int r1 = 1 * CC > lastrow ? lastrow : 1 * CC;
  int r2 = 2 * CC > lastrow ? lastrow : 2 * CC;
  int r3 = 3 * CC > lastrow ? lastrow : 3 * CC;
  float l0 = lg[r1 + c];
  float l1 = lg[r2 + c];
  float l2 = lg[r3 + c];

  // ---------- fused Viterbi + forward recursion ----------
  for (int t = 1; t < len; ++t) {
    float logit_c = l0;
    l0 = l1; l1 = l2;
    int rn = (t + 3) * CC;
    l2 = lg[(rn > lastrow ? lastrow : rn) + c];

    // candidates: S (viterbi, natural), F (forward, log2 domain)
    float S[16], F[16];
#pragma unroll
    for (int j = 0; j < 8; ++j) {
      S[2 * j]     = q[j].x + tr[2 * j];
      F[2 * j]     = q[j].y + tr2[2 * j];
      S[2 * j + 1] = q[j].z + tr[2 * j + 1];
      F[2 * j + 1] = q[j].w + tr2[2 * j + 1];
    }

    // forward local max (tree, depth 4)
    float g[8];
#pragma unroll
    for (int k = 0; k < 8; ++k) g[k] = fmaxf(F[k], F[k + 8]);
#pragma unroll
    for (int k = 0; k < 4; ++k) g[k] = fmaxf(g[k], g[k + 4]);
    float fmx = fmaxf(fmaxf(g[0], g[2]), fmaxf(g[1], g[3]));

    // exp against LOCAL max + pairwise sum
    float e[16];
#pragma unroll
    for (int i = 0; i < 16; ++i) e[i] = EXP2F(F[i] - fmx);
    float s8[8];
#pragma unroll
    for (int k = 0; k < 8; ++k) s8[k] = e[k] + e[k + 8];
    float s4a = s8[0] + s8[4], s4b = s8[1] + s8[5];
    float s4c = s8[2] + s8[6], s4d = s8[3] + s8[7];
    float sl = (s4a + s4b) + (s4c + s4d);

    // viterbi argmax: first-index-exact descending >= scan
    float gv[4]; int gi[4];
#pragma unroll
    for (int gg = 0; gg < 4; ++gg) {
      float bv = S[4 * gg + 3]; int bidx = 4 * gg + 3;
      if (S[4 * gg + 2] >= bv) { bv = S[4 * gg + 2]; bidx = 4 * gg + 2; }
      if (S[4 * gg + 1] >= bv) { bv = S[4 * gg + 1]; bidx = 4 * gg + 1; }
      if (S[4 * gg + 0] >= bv) { bv = S[4 * gg + 0]; bidx = 4 * gg + 0; }
      gv[gg] = bv; gi[gg] = bidx;
    }
    float best = gv[3]; int bi = gi[3];
    if (gv[2] >= best) { best = gv[2]; bi = gi[2]; }
    if (gv[1] >= best) { best = gv[1]; bi = gi[1]; }
    if (gv[0] >= best) { best = gv[0]; bi = gi[0]; }
    int bpi = h * 16 + bi;

    // single cross-half exchange round: 4 independent xor-32 shuffles
    float ov  = __shfl_xor(best, 32);
    int   oi  = __shfl_xor(bpi, 32);
    float ofm = __shfl_xor(fmx, 32);
    float os  = __shfl_xor(sl, 32);

    // viterbi combine (lower prev-tag wins ties; other half's oi vs mine)
    bool take = (ov > best) || (ov == best && oi < bpi);
    best = take ? ov : best;
    bpi  = take ? oi : bpi;
    av = logit_c + best;

    // forward combine with rescaling (explicit muls; order-independent)
    float m  = fmaxf(fmx, ofm);
    float ws = EXP2F(fmx - m);
    float wo = EXP2F(ofm - m);
    float ps = sl * ws;
    float po = os * wo;
    float s  = ps + po;
    A = logit_c * LOG2E + (m + LOG2F(s));

    if (h == 0) {
      ((float2*)axs)[c] = make_float2(av, A);      // one ds_write_b64
      bp_s[(t - 1) * CC + c] = (unsigned char)bpi;
    }
    // read next-step pairs (8 ds_read_b128, pipelined)
#pragma unroll
    for (int j = 0; j < 8; ++j) q[j] = axp[j];
  }

  // ---------- gold-path score (unary + binary), lane-parallel over t ----------
  float uacc = 0.0f, bacc = 0.0f;
#pragma unroll
  for (int j = 0; j < 8; ++j) {
    int t = lane + 64 * j;
    if (t < len) {
      int lt = lab[t];
      uacc += lg[t * CC + lt];
      if (t + 1 < len) {
        int ln = lab[t + 1];
        bacc += trans[lt * CC + ln];
      }
    }
  }
#pragma unroll
  for (int d = 32; d >= 1; d >>= 1) {
    uacc += __shfl_xor(uacc, d);
    bacc += __shfl_xor(bacc, d);
  }

  // ---------- last tag: argmax over c (first index on ties; h0 authoritative) ----------
  float v = av; int idx = c;
#pragma unroll
  for (int d = 1; d < 32; d <<= 1) {
    float v2 = __shfl_xor(v, d, 32);
    int   i2 = __shfl_xor(idx, d, 32);
    if (v2 > v || (v2 == v && i2 < idx)) { v = v2; idx = i2; }
  }

  // ---------- log partition (log2 domain -> natural) ----------
  float mm = A;
#pragma unroll
  for (int d = 1; d < 32; d <<= 1) mm = fmaxf(mm, __shfl_xor(mm, d, 32));
  float ss = EXP2F(A - mm);
#pragma unroll
  for (int d = 1; d < 32; d <<= 1) ss += __shfl_xor(ss, d, 32);
  float log_norm = LN2 * (mm + LOG2F(ss));

  // ---------- backtrace: register-prefetched rows, in-register byte select ----------
  if (lane == 0) {
    int tag = idx;
    tag_s[len - 1] = (unsigned char)tag;
    const uint4* bp4 = (const uint4*)bp_s;     // row r = bp4[2r], bp4[2r+1]
    uint4 Ra[3], Rb[3];
#pragma unroll
    for (int k = 0; k < 3; ++k) {
      int r = len - 2 - k;
      if (r >= 0) { Ra[k] = bp4[2 * r]; Rb[k] = bp4[2 * r + 1]; }
    }
    for (int t = len - 1; t > 0; --t) {
      uint4 ua = Ra[0], ub = Rb[0];
      Ra[0] = Ra[1]; Rb[0] = Rb[1];
      Ra[1] = Ra[2]; Rb[1] = Rb[2];
      int r = t - 4;                            // row consumed 3 iters ahead
      if (r >= 0) { Ra[2] = bp4[2 * r]; Rb[2] = bp4[2 * r + 1]; }
      // select byte `tag` from the 32-byte row (ua,ub)
      uint4 u4;
      u4.x = (tag & 16) ? ub.x : ua.x;
      u4.y = (tag & 16) ? ub.y : ua.y;
      u4.z = (tag & 16) ? ub.z : ua.z;
      u4.w = (tag & 16) ? ub.w : ua.w;
      unsigned lo = (tag & 8) ? u4.z : u4.x;
      unsigned hi = (tag & 8) ? u4.w : u4.y;
      unsigned u1 = (tag & 4) ? hi : lo;
      tag = (int)((u1 >> ((tag & 3) * 8)) & 0xffu);
      tag_s[t - 1] = (unsigned char)tag;
    }

    float ll = uacc + bacc - log_norm;
    atomicAdd(out + (size_t)BB * TT, -ll * (1.0f / BB));
  }

  // ---------- coalesced tag store (+ zero padding) ----------
#pragma unroll
  for (int j = 0; j < 8; ++j) {
    int t = lane + 64 * j;
    float val = (t < len) ? (float)tag_s[t] : 0.0f;
    out[bT + t] = val;
  }
}

extern "C" void kernel_launch(void* const* d_in, const int* in_sizes, int n_in,
                              void* d_out, int out_size, void* d_ws, size_t ws_size,
                              hipStream_t stream) {
  const float* logits = (const float*)d_in[0];
  const int*   seqlen = (const int*)d_in[1];
  const int*   labels = (const int*)d_in[2];
  const float* trans  = (const float*)d_in[3];
  float* out = (float*)d_out;

  zero_loss_kernel<<<1, 64, 0, stream>>>(out);
  crf_kernel<<<dim3(BB), dim3(64), 0, stream>>>(logits, seqlen, labels, trans, out);
}

// Round 6
// 556.710 us; speedup vs baseline: 1.0875x; 1.0583x over previous
//
#include <hip/hip_runtime.h>
#include <math.h>

// CRF layer: B=2048 sequences, T=512 max steps, C=32 tags.
// out = [ tags as float (B*T) | loss (1) ], total 1048577 floats.
#define BB 2048
#define TT 512
#define CC 32

#if __has_builtin(__builtin_amdgcn_exp2f)
#define EXP2F __builtin_amdgcn_exp2f
#else
#define EXP2F exp2f
#endif
#if __has_builtin(__builtin_amdgcn_logf)
#define LOG2F __builtin_amdgcn_logf   // v_log_f32 computes log2
#else
#define LOG2F log2f
#endif

#define LOG2E 1.4426950408889634f
#define LN2   0.6931471805599453f

__global__ void zero_loss_kernel(float* __restrict__ out) {
  if (threadIdx.x == 0) out[(size_t)BB * TT] = 0.0f;
}

// Two waves per block, one batch element per block.
//   wave 0: Viterbi recursion + backtrace + tag output.
//   wave 1: forward (logsumexp) recursion + gold-path score + loss.
// The two recurrences are independent; splitting them halves each wave's
// per-step dependency chain (4 ds_read_b128 + 2 shuffles + 1 ds_write each,
// instead of 8 reads + 4 shuffles + write fused). Waves never sync.
// Within a wave, LDS write -> read needs no barrier (DS pipe is in-order).
// lane = h*32 + c : c = tag, h = which 16 prev-tags this lane reduces over.
__global__ __launch_bounds__(128, 4) void crf_kernel(
    const float* __restrict__ logits,     // [B, T, C]
    const int*   __restrict__ seqlen,     // [B]
    const int*   __restrict__ labels,     // [B, T]
    const float* __restrict__ trans,      // [C, C]  trans[p*C + c]
    float*       __restrict__ out)        // [B*T + 1]
{
  __shared__ __align__(16) unsigned char bp_s[(TT - 1) * CC]; // 16,352 B
  __shared__ __align__(16) float avs[CC];       // viterbi alpha (natural)
  __shared__ __align__(16) float afs[CC];       // forward log2-alpha
  __shared__ unsigned char tag_s[TT];

  const int lane = threadIdx.x & 63;
  const int wv   = threadIdx.x >> 6;     // 0 = viterbi, 1 = forward
  const int c    = lane & 31;
  const int h    = lane >> 5;
  const int b    = blockIdx.x;

  const int len = seqlen[b];
  const float* lg = logits + (size_t)b * TT * CC;
  const size_t bT = (size_t)b * TT;

  // logits register pipeline bounds (both waves)
  const int lastrow = (len - 1) * CC;

  if (wv == 0) {
    // ================= Viterbi wave =================
    float tr[16];
#pragma unroll
    for (int i = 0; i < 16; ++i) tr[i] = trans[(h * 16 + i) * CC + c];

    float av = lg[c];
    if (h == 0) avs[c] = av;

    int r1 = 1 * CC > lastrow ? lastrow : 1 * CC;
    int r2 = 2 * CC > lastrow ? lastrow : 2 * CC;
    int r3 = 3 * CC > lastrow ? lastrow : 3 * CC;
    float l0 = lg[r1 + c];
    float l1 = lg[r2 + c];
    float l2 = lg[r3 + c];

    const float4* avp = (const float4*)(avs + h * 16);

    for (int t = 1; t < len; ++t) {
      float logit_c = l0;
      l0 = l1; l1 = l2;
      int rn = (t + 3) * CC;
      l2 = lg[(rn > lastrow ? lastrow : rn) + c];

      // my half's 16 prev alphas (4x ds_read_b128, broadcast across lanes)
      float pav[16];
#pragma unroll
      for (int qq = 0; qq < 4; ++qq) ((float4*)pav)[qq] = avp[qq];

      float S[16];
#pragma unroll
      for (int i = 0; i < 16; ++i) S[i] = pav[i] + tr[i];

      // first-index-exact argmax: descending >= scan (proven R3/R4)
      float gv[4]; int gi[4];
#pragma unroll
      for (int gg = 0; gg < 4; ++gg) {
        float bv = S[4 * gg + 3]; int bidx = 4 * gg + 3;
        if (S[4 * gg + 2] >= bv) { bv = S[4 * gg + 2]; bidx = 4 * gg + 2; }
        if (S[4 * gg + 1] >= bv) { bv = S[4 * gg + 1]; bidx = 4 * gg + 1; }
        if (S[4 * gg + 0] >= bv) { bv = S[4 * gg + 0]; bidx = 4 * gg + 0; }
        gv[gg] = bv; gi[gg] = bidx;
      }
      float best = gv[3]; int bi = gi[3];
      if (gv[2] >= best) { best = gv[2]; bi = gi[2]; }
      if (gv[1] >= best) { best = gv[1]; bi = gi[1]; }
      if (gv[0] >= best) { best = gv[0]; bi = gi[0]; }
      int bpi = h * 16 + bi;

      // single cross-half exchange round (2 independent shuffles)
      float ov = __shfl_xor(best, 32);
      int   oi = __shfl_xor(bpi, 32);
      bool take = (ov > best) || (ov == best && oi < bpi);
      best = take ? ov : best;
      bpi  = take ? oi : bpi;
      av = logit_c + best;

      if (h == 0) {
        avs[c] = av;                             // ds_write_b32
        bp_s[(t - 1) * CC + c] = (unsigned char)bpi;
      }
    }

    // last tag: argmax over c (first index on ties)
    float v = av; int idx = c;
#pragma unroll
    for (int d = 1; d < 32; d <<= 1) {
      float v2 = __shfl_xor(v, d, 32);
      int   i2 = __shfl_xor(idx, d, 32);
      if (v2 > v || (v2 == v && i2 < idx)) { v = v2; idx = i2; }
    }

    // backtrace: register-prefetched rows, in-register byte select (R4)
    if (lane == 0) {
      int tag = idx;
      tag_s[len - 1] = (unsigned char)tag;
      const uint4* bp4 = (const uint4*)bp_s;   // row r = bp4[2r], bp4[2r+1]
      uint4 Ra[3], Rb[3];
#pragma unroll
      for (int k = 0; k < 3; ++k) {
        int r = len - 2 - k;
        if (r >= 0) { Ra[k] = bp4[2 * r]; Rb[k] = bp4[2 * r + 1]; }
      }
      for (int tt = len - 1; tt > 0; --tt) {
        uint4 ua = Ra[0], ub = Rb[0];
        Ra[0] = Ra[1]; Rb[0] = Rb[1];
        Ra[1] = Ra[2]; Rb[1] = Rb[2];
        int r = tt - 4;
        if (r >= 0) { Ra[2] = bp4[2 * r]; Rb[2] = bp4[2 * r + 1]; }
        uint4 u4;
        u4.x = (tag & 16) ? ub.x : ua.x;
        u4.y = (tag & 16) ? ub.y : ua.y;
        u4.z = (tag & 16) ? ub.z : ua.z;
        u4.w = (tag & 16) ? ub.w : ua.w;
        unsigned lo = (tag & 8) ? u4.z : u4.x;
        unsigned hi = (tag & 8) ? u4.w : u4.y;
        unsigned u1 = (tag & 4) ? hi : lo;
        tag = (int)((u1 >> ((tag & 3) * 8)) & 0xffu);
        tag_s[tt - 1] = (unsigned char)tag;
      }
    }

    // coalesced tag store (+ zero padding)
#pragma unroll
    for (int j = 0; j < 8; ++j) {
      int tt = lane + 64 * j;
      float val = (tt < len) ? (float)tag_s[tt] : 0.0f;
      out[bT + tt] = val;
    }

  } else {
    // ================= Forward wave =================
    const int* lab = labels + (size_t)b * TT;

    float tr2[16];
#pragma unroll
    for (int i = 0; i < 16; ++i)
      tr2[i] = trans[(h * 16 + i) * CC + c] * LOG2E;

    float A = lg[c] * LOG2E;
    if (h == 0) afs[c] = A;

    int r1 = 1 * CC > lastrow ? lastrow : 1 * CC;
    int r2 = 2 * CC > lastrow ? lastrow : 2 * CC;
    int r3 = 3 * CC > lastrow ? lastrow : 3 * CC;
    float l0 = lg[r1 + c];
    float l1 = lg[r2 + c];
    float l2 = lg[r3 + c];

    const float4* afp = (const float4*)(afs + h * 16);

    for (int t = 1; t < len; ++t) {
      float logit_c = l0;
      l0 = l1; l1 = l2;
      int rn = (t + 3) * CC;
      l2 = lg[(rn > lastrow ? lastrow : rn) + c];

      float paf[16];
#pragma unroll
      for (int qq = 0; qq < 4; ++qq) ((float4*)paf)[qq] = afp[qq];

      float F[16];
#pragma unroll
      for (int i = 0; i < 16; ++i) F[i] = paf[i] + tr2[i];

      // local max (tree)
      float g8[8];
#pragma unroll
      for (int k = 0; k < 8; ++k) g8[k] = fmaxf(F[k], F[k + 8]);
#pragma unroll
      for (int k = 0; k < 4; ++k) g8[k] = fmaxf(g8[k], g8[k + 4]);
      float fmx = fmaxf(fmaxf(g8[0], g8[2]), fmaxf(g8[1], g8[3]));

      // exp against LOCAL max + pairwise sum
      float e[16];
#pragma unroll
      for (int i = 0; i < 16; ++i) e[i] = EXP2F(F[i] - fmx);
      float s8[8];
#pragma unroll
      for (int k = 0; k < 8; ++k) s8[k] = e[k] + e[k + 8];
      float s4a = s8[0] + s8[4], s4b = s8[1] + s8[5];
      float s4c = s8[2] + s8[6], s4d = s8[3] + s8[7];
      float sl = (s4a + s4b) + (s4c + s4d);

      // single cross-half exchange round (2 independent shuffles)
      float ofm = __shfl_xor(fmx, 32);
      float os  = __shfl_xor(sl, 32);

      // combine with rescaling (commutative-exact; both halves identical)
      float m  = fmaxf(fmx, ofm);
      float ws = EXP2F(fmx - m);
      float wo = EXP2F(ofm - m);
      float ps = sl * ws;
      float po = os * wo;
      float s  = ps + po;
      A = logit_c * LOG2E + (m + LOG2F(s));

      if (h == 0) afs[c] = A;                    // ds_write_b32
    }

    // gold-path score (unary + binary), lane-parallel over t
    float uacc = 0.0f, bacc = 0.0f;
#pragma unroll
    for (int j = 0; j < 8; ++j) {
      int tt = lane + 64 * j;
      if (tt < len) {
        int lt = lab[tt];
        uacc += lg[tt * CC + lt];
        if (tt + 1 < len) {
          int ln = lab[tt + 1];
          bacc += trans[lt * CC + ln];
        }
      }
    }
#pragma unroll
    for (int d = 32; d >= 1; d >>= 1) {
      uacc += __shfl_xor(uacc, d);
      bacc += __shfl_xor(bacc, d);
    }

    // log partition (log2 domain -> natural)
    float mm = A;
#pragma unroll
    for (int d = 1; d < 32; d <<= 1) mm = fmaxf(mm, __shfl_xor(mm, d, 32));
    float ss = EXP2F(A - mm);
#pragma unroll
    for (int d = 1; d < 32; d <<= 1) ss += __shfl_xor(ss, d, 32);
    float log_norm = LN2 * (mm + LOG2F(ss));

    if (lane == 0) {
      float ll = uacc + bacc - log_norm;
      atomicAdd(out + (size_t)BB * TT, -ll * (1.0f / BB));
    }
  }
}

extern "C" void kernel_launch(void* const* d_in, const int* in_sizes, int n_in,
                              void* d_out, int out_size, void* d_ws, size_t ws_size,
                              hipStream_t stream) {
  const float* logits = (const float*)d_in[0];
  const int*   seqlen = (const int*)d_in[1];
  const int*   labels = (const int*)d_in[2];
  const float* trans  = (const float*)d_in[3];
  float* out = (float*)d_out;

  zero_loss_kernel<<<1, 64, 0, stream>>>(out);
  crf_kernel<<<dim3(BB), dim3(128), 0, stream>>>(logits, seqlen, labels, trans, out);
}

// Round 7
// 553.990 us; speedup vs baseline: 1.0928x; 1.0049x over previous
//
#include <hip/hip_runtime.h>
#include <math.h>

// CRF layer: B=2048 sequences, T=512 max steps, C=32 tags.
// out = [ tags as float (B*T) | loss (1) ], total 1048577 floats.
#define BB 2048
#define TT 512
#define CC 32

#if __has_builtin(__builtin_amdgcn_exp2f)
#define EXP2F __builtin_amdgcn_exp2f
#else
#define EXP2F exp2f
#endif
#if __has_builtin(__builtin_amdgcn_logf)
#define LOG2F __builtin_amdgcn_logf   // v_log_f32 computes log2
#else
#define LOG2F log2f
#endif

#define LOG2E 1.4426950408889634f
#define LN2   0.6931471805599453f

__global__ void zero_loss_kernel(float* __restrict__ out) {
  if (threadIdx.x == 0) out[(size_t)BB * TT] = 0.0f;
}

// DPP row rotate-right by K: lane i reads lane (i-K)&15 within its 16-row.
// (AMD cross-lane docs: row_shr:1 reads thread_id-1; ror = shr w/ wrap.)
__device__ __forceinline__ float rotror(float x, int ctrl_unused) { return x; }
#define ROR(dst, src, K)                                                     \
  dst = __int_as_float(__builtin_amdgcn_update_dpp(                          \
      0, __float_as_int(src), 0x120 | (K), 0xF, 0xF, false));

// Two waves per block, one batch element per block.
//   wave 0 (V): Viterbi recursion via LDS alpha exchange + backtrace + tags.
//   wave 1 (F): forward logsumexp, alphas kept IN REGISTERS via DPP row
//               rotations; only 1 DS op (shfl_xor 16) per step.
// Waves never sync. Within a wave, LDS write->read needs no barrier.
__global__ __launch_bounds__(128, 4) void crf_kernel(
    const float* __restrict__ logits,     // [B, T, C]
    const int*   __restrict__ seqlen,     // [B]
    const int*   __restrict__ labels,     // [B, T]
    const float* __restrict__ trans,      // [C, C]  trans[p*C + c]
    float*       __restrict__ out)        // [B*T + 1]
{
  __shared__ __align__(16) unsigned char bp_s[(TT - 1) * CC]; // 16,352 B
  __shared__ __align__(16) float avs[CC];       // viterbi alpha (natural)
  __shared__ unsigned char tag_s[TT];

  const int lane = threadIdx.x & 63;
  const int wv   = threadIdx.x >> 6;     // 0 = viterbi, 1 = forward
  const int b    = blockIdx.x;

  const int len = seqlen[b];
  const float* lg = logits + (size_t)b * TT * CC;
  const size_t bT = (size_t)b * TT;

  if (wv == 0) {
    // ================= Viterbi wave (LDS-based, proven-exact core) =========
    const int c = lane & 31;
    const int h = lane >> 5;

    float tr[16];
#pragma unroll
    for (int i = 0; i < 16; ++i) tr[i] = trans[(h * 16 + i) * CC + c];

    float av = lg[c];
    if (h == 0) avs[c] = av;

    const float4* avp = (const float4*)(avs + h * 16);

    // 3-deep logit prefetch, unclamped main loop + clamped tail
    const float* lgc = lg + c;
    float l0 = 0, l1 = 0, l2 = 0;
    {
      int r1 = 1 < len ? 1 : len - 1;
      int r2 = 2 < len ? 2 : len - 1;
      int r3 = 3 < len ? 3 : len - 1;
      l0 = lgc[r1 * CC]; l1 = lgc[r2 * CC]; l2 = lgc[r3 * CC];
    }

    auto vstep = [&](int t, float logit_c) {
      float pav[16];
#pragma unroll
      for (int qq = 0; qq < 4; ++qq) ((float4*)pav)[qq] = avp[qq];

      float S[16];
#pragma unroll
      for (int i = 0; i < 16; ++i) S[i] = pav[i] + tr[i];

      // tree max (depth 4)
      float m8[8];
#pragma unroll
      for (int k = 0; k < 8; ++k) m8[k] = fmaxf(S[k], S[k + 8]);
#pragma unroll
      for (int k = 0; k < 4; ++k) m8[k] = fmaxf(m8[k], m8[k + 4]);
      float best = fmaxf(fmaxf(m8[0], m8[2]), fmaxf(m8[1], m8[3]));

      // first-index = min index where equal (order-independent, exact)
      int t8[16];
#pragma unroll
      for (int i = 0; i < 16; ++i) t8[i] = (S[i] == best) ? i : 63;
#pragma unroll
      for (int k = 0; k < 8; ++k) t8[k] = min(t8[k], t8[k + 8]);
#pragma unroll
      for (int k = 0; k < 4; ++k) t8[k] = min(t8[k], t8[k + 4]);
      int bi = min(min(t8[0], t8[2]), min(t8[1], t8[3]));
      int bpi = h * 16 + bi;

      // cross-half combine (verbatim R6: lower prev-tag wins ties)
      float ov = __shfl_xor(best, 32);
      int   oi = __shfl_xor(bpi, 32);
      bool take = (ov > best) || (ov == best && oi < bpi);
      best = take ? ov : best;
      bpi  = take ? oi : bpi;
      av = logit_c + best;

      if (h == 0) {
        avs[c] = av;
        bp_s[(t - 1) * CC + c] = (unsigned char)bpi;
      }
    };

    int t = 1;
    int tmain = len - 3;                   // t+3 <= len-1 guaranteed
    for (; t < tmain; ++t) {
      float lc = l0; l0 = l1; l1 = l2;
      l2 = lgc[(t + 3) * CC];
      vstep(t, lc);
    }
    for (; t < len; ++t) {
      float lc = l0; l0 = l1; l1 = l2;
      int rn = t + 3; rn = rn < len ? rn : len - 1;
      l2 = lgc[rn * CC];
      vstep(t, lc);
    }

    // last tag: argmax over c (first index on ties)
    float v = av; int idx = c;
#pragma unroll
    for (int d = 1; d < 32; d <<= 1) {
      float v2 = __shfl_xor(v, d, 32);
      int   i2 = __shfl_xor(idx, d, 32);
      if (v2 > v || (v2 == v && i2 < idx)) { v = v2; idx = i2; }
    }

    // backtrace: register-prefetched rows, in-register byte select
    if (lane == 0) {
      int tag = idx;
      tag_s[len - 1] = (unsigned char)tag;
      const uint4* bp4 = (const uint4*)bp_s;   // row r = bp4[2r], bp4[2r+1]
      uint4 Ra[3], Rb[3];
#pragma unroll
      for (int k = 0; k < 3; ++k) {
        int r = len - 2 - k;
        if (r >= 0) { Ra[k] = bp4[2 * r]; Rb[k] = bp4[2 * r + 1]; }
      }
      for (int tt = len - 1; tt > 0; --tt) {
        uint4 ua = Ra[0], ub = Rb[0];
        Ra[0] = Ra[1]; Rb[0] = Rb[1];
        Ra[1] = Ra[2]; Rb[1] = Rb[2];
        int r = tt - 4;
        if (r >= 0) { Ra[2] = bp4[2 * r]; Rb[2] = bp4[2 * r + 1]; }
        uint4 u4;
        u4.x = (tag & 16) ? ub.x : ua.x;
        u4.y = (tag & 16) ? ub.y : ua.y;
        u4.z = (tag & 16) ? ub.z : ua.z;
        u4.w = (tag & 16) ? ub.w : ua.w;
        unsigned lo = (tag & 8) ? u4.z : u4.x;
        unsigned hi = (tag & 8) ? u4.w : u4.y;
        unsigned u1 = (tag & 4) ? hi : lo;
        tag = (int)((u1 >> ((tag & 3) * 8)) & 0xffu);
        tag_s[tt - 1] = (unsigned char)tag;
      }
    }

    // coalesced tag store (+ zero padding)
#pragma unroll
    for (int j = 0; j < 8; ++j) {
      int tt = lane + 64 * j;
      float val = (tt < len) ? (float)tag_s[tt] : 0.0f;
      out[bT + tt] = val;
    }

  } else {
    // ================= Forward wave (register alphas, DPP rotation) ========
    const int* lab = labels + (size_t)b * TT;
    const int i = lane & 15;
    const int r = (lane >> 4) & 1;
    const int c = lane & 31;              // c == r*16 + i; lanes 32-63 mirror

    // transitions in rotation order: step k pairs with alpha from lane-k
    float trA[16], trB[16];
#pragma unroll
    for (int k = 0; k < 16; ++k) {
      int pA = r * 16 + ((i - k) & 15);
      int pB = (1 - r) * 16 + ((i - k) & 15);
      trA[k] = trans[pA * CC + c] * LOG2E;
      trB[k] = trans[pB * CC + c] * LOG2E;
    }

    float A = lg[c] * LOG2E;              // forward log2-alpha, in-register

    const float* lgc = lg + c;
    float l0 = 0, l1 = 0, l2 = 0;
    {
      int r1 = 1 < len ? 1 : len - 1;
      int r2 = 2 < len ? 2 : len - 1;
      int r3 = 3 < len ? 3 : len - 1;
      l0 = lgc[r1 * CC]; l1 = lgc[r2 * CC]; l2 = lgc[r3 * CC];
    }

    auto fstep = [&](float logit_c) {
      // other row's base alpha (1 DS op; overlaps with phase A below)
      float Bv = __shfl_xor(A, 16);

      // phase A: own row all-gather via DPP ror (VALU pipe)
      float FA[16];
      FA[0] = A + trA[0];
      {
        float x;
        ROR(x, A, 1);  FA[1]  = x + trA[1];
        ROR(x, A, 2);  FA[2]  = x + trA[2];
        ROR(x, A, 3);  FA[3]  = x + trA[3];
        ROR(x, A, 4);  FA[4]  = x + trA[4];
        ROR(x, A, 5);  FA[5]  = x + trA[5];
        ROR(x, A, 6);  FA[6]  = x + trA[6];
        ROR(x, A, 7);  FA[7]  = x + trA[7];
        ROR(x, A, 8);  FA[8]  = x + trA[8];
        ROR(x, A, 9);  FA[9]  = x + trA[9];
        ROR(x, A, 10); FA[10] = x + trA[10];
        ROR(x, A, 11); FA[11] = x + trA[11];
        ROR(x, A, 12); FA[12] = x + trA[12];
        ROR(x, A, 13); FA[13] = x + trA[13];
        ROR(x, A, 14); FA[14] = x + trA[14];
        ROR(x, A, 15); FA[15] = x + trA[15];
      }
      // phase B: other row via the swizzled base
      float FB[16];
      FB[0] = Bv + trB[0];
      {
        float x;
        ROR(x, Bv, 1);  FB[1]  = x + trB[1];
        ROR(x, Bv, 2);  FB[2]  = x + trB[2];
        ROR(x, Bv, 3);  FB[3]  = x + trB[3];
        ROR(x, Bv, 4);  FB[4]  = x + trB[4];
        ROR(x, Bv, 5);  FB[5]  = x + trB[5];
        ROR(x, Bv, 6);  FB[6]  = x + trB[6];
        ROR(x, Bv, 7);  FB[7]  = x + trB[7];
        ROR(x, Bv, 8);  FB[8]  = x + trB[8];
        ROR(x, Bv, 9);  FB[9]  = x + trB[9];
        ROR(x, Bv, 10); FB[10] = x + trB[10];
        ROR(x, Bv, 11); FB[11] = x + trB[11];
        ROR(x, Bv, 12); FB[12] = x + trB[12];
        ROR(x, Bv, 13); FB[13] = x + trB[13];
        ROR(x, Bv, 14); FB[14] = x + trB[14];
        ROR(x, Bv, 15); FB[15] = x + trB[15];
      }

      // global max (tree over 32)
      float g[16];
#pragma unroll
      for (int k = 0; k < 16; ++k) g[k] = fmaxf(FA[k], FB[k]);
#pragma unroll
      for (int k = 0; k < 8; ++k) g[k] = fmaxf(g[k], g[k + 8]);
#pragma unroll
      for (int k = 0; k < 4; ++k) g[k] = fmaxf(g[k], g[k + 4]);
      float m = fmaxf(fmaxf(g[0], g[2]), fmaxf(g[1], g[3]));

      // exp + sum (32 exps)
      float s = 0.0f;
      float eA[16], eB[16];
#pragma unroll
      for (int k = 0; k < 16; ++k) eA[k] = EXP2F(FA[k] - m);
#pragma unroll
      for (int k = 0; k < 16; ++k) eB[k] = EXP2F(FB[k] - m);
      float s16[16];
#pragma unroll
      for (int k = 0; k < 16; ++k) s16[k] = eA[k] + eB[k];
#pragma unroll
      for (int k = 0; k < 8; ++k) s16[k] = s16[k] + s16[k + 8];
#pragma unroll
      for (int k = 0; k < 4; ++k) s16[k] = s16[k] + s16[k + 4];
      s = (s16[0] + s16[2]) + (s16[1] + s16[3]);

      A = logit_c * LOG2E + (m + LOG2F(s));
    };

    int t = 1;
    int tmain = len - 3;
    for (; t < tmain; ++t) {
      float lc = l0; l0 = l1; l1 = l2;
      l2 = lgc[(t + 3) * CC];
      fstep(lc);
    }
    for (; t < len; ++t) {
      float lc = l0; l0 = l1; l1 = l2;
      int rn = t + 3; rn = rn < len ? rn : len - 1;
      l2 = lgc[rn * CC];
      fstep(lc);
    }

    // gold-path score (unary + binary), lane-parallel over t
    float uacc = 0.0f, bacc = 0.0f;
#pragma unroll
    for (int j = 0; j < 8; ++j) {
      int tt = lane + 64 * j;
      if (tt < len) {
        int lt = lab[tt];
        uacc += lg[tt * CC + lt];
        if (tt + 1 < len) {
          int ln = lab[tt + 1];
          bacc += trans[lt * CC + ln];
        }
      }
    }
#pragma unroll
    for (int d = 32; d >= 1; d >>= 1) {
      uacc += __shfl_xor(uacc, d);
      bacc += __shfl_xor(bacc, d);
    }

    // log partition (log2 domain -> natural)
    float mm = A;
#pragma unroll
    for (int d = 1; d < 32; d <<= 1) mm = fmaxf(mm, __shfl_xor(mm, d, 32));
    float ss = EXP2F(A - mm);
#pragma unroll
    for (int d = 1; d < 32; d <<= 1) ss += __shfl_xor(ss, d, 32);
    float log_norm = LN2 * (mm + LOG2F(ss));

    if (lane == 0) {
      float ll = uacc + bacc - log_norm;
      atomicAdd(out + (size_t)BB * TT, -ll * (1.0f / BB));
    }
  }
}

extern "C" void kernel_launch(void* const* d_in, const int* in_sizes, int n_in,
                              void* d_out, int out_size, void* d_ws, size_t ws_size,
                              hipStream_t stream) {
  const float* logits = (const float*)d_in[0];
  const int*   seqlen = (const int*)d_in[1];
  const int*   labels = (const int*)d_in[2];
  const float* trans  = (const float*)d_in[3];
  float* out = (float*)d_out;

  zero_loss_kernel<<<1, 64, 0, stream>>>(out);
  crf_kernel<<<dim3(BB), dim3(128), 0, stream>>>(logits, seqlen, labels, trans, out);
}